// Round 4
// baseline (894.075 us; speedup 1.0000x reference)
//
#include <hip/hip_runtime.h>
#include <math.h>

typedef _Float16 h16;
typedef _Float16 v2h __attribute__((ext_vector_type(2)));

#define ALPHA 0.2f
#define MASKV -9000000000000000.0f

constexpr int GSCR = 268;   // floats per group scratch slot
constexpr int O_S  = 0;     // s[27] f32
constexpr int O_F1 = 28;    // f1[27] f32
constexpr int O_F2 = 56;    // f2[3][10] f32
constexpr int O_U  = 92;    // byte 368 (16B aligned): h1 tile [9][32] f16 / att [27][12] f16
// h2 overlay lives at group base (floats 0..215): used only after s/f1/f2/att are dead.

#if defined(__has_builtin)
#  if __has_builtin(__builtin_amdgcn_fdot2)
#    define FDOT2(a,b,c) __builtin_amdgcn_fdot2((a),(b),(c),false)
#  endif
#endif
#ifndef FDOT2
__device__ __forceinline__ float fdot2_sw(v2h a, v2h b, float c) {
    return c + (float)a.x*(float)b.x + (float)a.y*(float)b.y;
}
#  define FDOT2(a,b,c) fdot2_sw((a),(b),(c))
#endif

union U4 { float4 f; v2h h[4]; };
union U2 { float2 f; v2h h[2]; };
union U1 { float  f; v2h h;    };

#define WAVE_SYNC() asm volatile("s_waitcnt lgkmcnt(0)" ::: "memory")

__device__ __forceinline__ float fast_rcp(float x) { return __builtin_amdgcn_rcpf(x); }
__device__ __forceinline__ float tanh_fast(float x) {
    float e = __expf(x + x);
    return 1.f - 2.f * fast_rcp(e + 1.f);
}

// ws layout (halves): [0,4608): w2H[c][i] (48x96)  [4608,5760): wp1P pair-slots
__global__ void prep_kernel(const float* __restrict__ W2, const float* __restrict__ Wp1,
                            h16* __restrict__ ws) {
    int t = blockIdx.x * 256 + threadIdx.x;
    if (t < 48 * 96) {
        int c = t / 96, i = t - c * 96;
        int h = c >> 4, d = c & 15;
        ws[t] = (h16)W2[(h * 96 + i) * 16 + d];
    } else if (t < 48 * 96 + 576) {
        int t2 = t - 48 * 96;
        int k = t2 / 24, s = t2 - k * 24;
        int l = s / 3, kp = s - 3 * l;
        int clo = l + 16 * kp, chi = clo + 8;
        ws[4608 + 2 * t2]     = (h16)Wp1[clo * 24 + k];
        ws[4608 + 2 * t2 + 1] = (h16)Wp1[chi * 24 + k];
    }
}

// launch_bounds(128,2): min-2-waves/EU keeps the VGPR budget at 256 so the
// 54-reg accumulator never spills. (128,4) made the backend target 64 VGPRs
// and spill acc -> 350 MB of scratch HBM traffic (round-3 counters).
__global__ __launch_bounds__(128, 2) void gnn_gat_kernel(
    const float* __restrict__ obs, const float* __restrict__ adj,
    const float* __restrict__ W1,  const float* __restrict__ a1,
    const float* __restrict__ a2,  const float* __restrict__ bp1,
    const float* __restrict__ Wp2, const h16* __restrict__ ws,
    float* __restrict__ out, int B)
{
    __shared__ float sW1[96];
    __shared__ float sAdj[81];
    __shared__ float sC12[6];
    __shared__ __align__(16) float smem[16 * GSCR];

    const int tid = threadIdx.x;
    if (tid < 96) sW1[tid] = W1[tid];
    if (tid < 81) sAdj[tid] = adj[tid];
    if (tid < 6) {
        int gg = tid >> 1, w = tid & 1;
        float s = 0.f;
        for (int d = 0; d < 32; ++d)
            s += W1[gg * 32 + d] * a1[gg * 64 + w * 32 + d];
        sC12[tid] = s;
    }
    __syncthreads();

    const int wv = tid >> 6, lane = tid & 63;
    const int q = lane >> 3, l8 = lane & 7;
    float* g = smem + (wv * 8 + q) * GSCR;
    float4* hUf4 = (float4*)(g + O_U);            // h1 tile rows: 4 float4 each
    float4* h2f4 = (float4*)g;                    // h2 rows: 6 float4 each
    const float4* wsf4 = (const float4*)ws;

    float c12[6];
    #pragma unroll
    for (int i = 0; i < 6; ++i) c12[i] = sC12[i];
    float a2a0[3], a2a1[3], a2b0[3], a2b1[3];
    #pragma unroll
    for (int h = 0; h < 3; ++h) {
        a2a0[h] = a2[h * 32 + l8];
        a2a1[h] = a2[h * 32 + 8 + l8];
        a2b0[h] = a2[h * 32 + 16 + l8];
        a2b1[h] = a2[h * 32 + 24 + l8];
    }
    unsigned am[3];
    #pragma unroll
    for (int r = 0; r < 3; ++r) {
        unsigned u = 0;
        for (int t = 0; t < 27; ++t)
            u |= (sAdj[r * 27 + t] > 0.f ? 1u : 0u) << t;
        am[r] = u;
    }
    float wq[3], bq[3];
    #pragma unroll
    for (int kk = 0; kk < 3; ++kk) {
        wq[kk] = Wp2[l8 + 8 * kk];
        bq[kk] = bp1[l8 + 8 * kk];
    }

    const int slots = gridDim.x * 16;
    for (int b = (blockIdx.x * 2 + wv) * 8 + q; b < B; b += slots) {
        // ---- A: obs (group-broadcast loads) ----
        float o_r[9];
        #pragma unroll
        for (int j = 0; j < 9; ++j) o_r[j] = obs[(size_t)b * 9 + j];

        // ---- B: layer-1 collapsed attention -> s[g][n] in LDS ----
        for (int t = l8; t < 27; t += 8) {
            int gg = (t >= 18) ? 2 : (t >= 9 ? 1 : 0);
            int n = t - 9 * gg;
            float f1 = c12[2 * gg] * o_r[n];
            float c2 = c12[2 * gg + 1];
            unsigned rbits = (am[n / 3] >> (9 * (n % 3))) & 0x1FFu;
            float e[9], m = -3.0e38f;
            #pragma unroll
            for (int j = 0; j < 9; ++j) {
                float x = f1 + c2 * o_r[j];
                x = x > 0.f ? x : ALPHA * x;
                x = ((rbits >> j) & 1) ? x : MASKV;
                e[j] = x; m = fmaxf(m, x);
            }
            float sum = 0.f, sw = 0.f;
            #pragma unroll
            for (int j = 0; j < 9; ++j) {
                float p = __expf(e[j] - m);
                sum += p; sw += p * o_r[j];
            }
            g[O_S + t] = sw * fast_rcp(sum);
        }
        WAVE_SYNC();

        // ---- C/D: 3 K-tiles of 32; h1 f16 in LDS, GEMM via v_dot2 ----
        float acc[9][6];
        #pragma unroll
        for (int n = 0; n < 9; ++n)
            #pragma unroll
            for (int k = 0; k < 6; ++k) acc[n][k] = 0.f;

        for (int p = 0; p < 3; ++p) {
            // C: h1[n][0..31] = elu(s[p][n] * W1[32p..32p+31]) as f16
            #pragma unroll
            for (int it = 0; it < 5; ++it) {
                int t = l8 + 8 * it;
                if (t < 36) {
                    int n = t >> 2, ib = t & 3;
                    int i0 = 32 * p + 8 * ib;
                    float sv = g[O_S + p * 9 + n];
                    float4 wa = *(const float4*)&sW1[i0];
                    float4 wb = *(const float4*)&sW1[i0 + 4];
                    float v0 = sv * wa.x, v1 = sv * wa.y, v2 = sv * wa.z, v3 = sv * wa.w;
                    float v4 = sv * wb.x, v5 = sv * wb.y, v6 = sv * wb.z, v7 = sv * wb.w;
                    v0 = v0 > 0.f ? v0 : __expf(v0) - 1.f;
                    v1 = v1 > 0.f ? v1 : __expf(v1) - 1.f;
                    v2 = v2 > 0.f ? v2 : __expf(v2) - 1.f;
                    v3 = v3 > 0.f ? v3 : __expf(v3) - 1.f;
                    v4 = v4 > 0.f ? v4 : __expf(v4) - 1.f;
                    v5 = v5 > 0.f ? v5 : __expf(v5) - 1.f;
                    v6 = v6 > 0.f ? v6 : __expf(v6) - 1.f;
                    v7 = v7 > 0.f ? v7 : __expf(v7) - 1.f;
                    U4 u;
                    u.h[0] = (v2h){(h16)v0, (h16)v1};
                    u.h[1] = (v2h){(h16)v2, (h16)v3};
                    u.h[2] = (v2h){(h16)v4, (h16)v5};
                    u.h[3] = (v2h){(h16)v6, (h16)v7};
                    hUf4[n * 4 + ib] = u.f;
                }
            }
            WAVE_SYNC();

            // D: acc[n][k] += h1[n][i:i+8] . w2[c][i:i+8]
            #pragma unroll
            for (int ib = 0; ib < 4; ++ib) {
                U4 w[6];
                #pragma unroll
                for (int k = 0; k < 6; ++k)
                    w[k].f = wsf4[(l8 + 8 * k) * 12 + p * 4 + ib];
                #pragma unroll
                for (int n = 0; n < 9; ++n) {
                    U4 hh; hh.f = hUf4[n * 4 + ib];
                    #pragma unroll
                    for (int k = 0; k < 6; ++k) {
                        float a = acc[n][k];
                        a = FDOT2(hh.h[0], w[k].h[0], a);
                        a = FDOT2(hh.h[1], w[k].h[1], a);
                        a = FDOT2(hh.h[2], w[k].h[2], a);
                        a = FDOT2(hh.h[3], w[k].h[3], a);
                        acc[n][k] = a;
                    }
                }
            }
            WAVE_SYNC();
        }

        // ---- f1/f2 for layer-2 attention (butterfly over 8 d-lanes) ----
        #pragma unroll
        for (int h = 0; h < 3; ++h) {
            #pragma unroll
            for (int n = 0; n < 9; ++n) {
                float v1 = acc[n][2 * h] * a2a0[h] + acc[n][2 * h + 1] * a2a1[h];
                float v2 = acc[n][2 * h] * a2b0[h] + acc[n][2 * h + 1] * a2b1[h];
                v1 += __shfl_xor(v1, 1, 8); v1 += __shfl_xor(v1, 2, 8); v1 += __shfl_xor(v1, 4, 8);
                v2 += __shfl_xor(v2, 1, 8); v2 += __shfl_xor(v2, 2, 8); v2 += __shfl_xor(v2, 4, 8);
                if (((h * 9 + n) & 7) == l8) {
                    g[O_F1 + h * 9 + n]  = v1;
                    g[O_F2 + h * 10 + n] = v2;
                }
            }
        }
        WAVE_SYNC();

        // ---- E1: att rows -> f16 LDS [27][12] ----
        for (int t = l8; t < 27; t += 8) {
            int h = (t >= 18) ? 2 : (t >= 9 ? 1 : 0);
            int i = t - 9 * h;
            float f1i = g[O_F1 + t];
            float f2r[9];
            #pragma unroll
            for (int j = 0; j < 9; ++j) f2r[j] = g[O_F2 + h * 10 + j];
            unsigned rbits = (am[i / 3] >> (9 * (i % 3))) & 0x1FFu;
            float e[9], m = -3.0e38f;
            #pragma unroll
            for (int j = 0; j < 9; ++j) {
                float x = f1i + f2r[j];
                x = x > 0.f ? x : ALPHA * x;
                x = ((rbits >> j) & 1) ? x : MASKV;
                e[j] = x; m = fmaxf(m, x);
            }
            float p[9], sum = 0.f;
            #pragma unroll
            for (int j = 0; j < 9; ++j) { p[j] = __expf(e[j] - m); sum += p[j]; }
            float r = fast_rcp(sum);
            char* row = (char*)(g + O_U) + t * 24;
            U2 u01, u23; U1 u4;
            u01.h[0] = (v2h){(h16)(p[0] * r), (h16)(p[1] * r)};
            u01.h[1] = (v2h){(h16)(p[2] * r), (h16)(p[3] * r)};
            u23.h[0] = (v2h){(h16)(p[4] * r), (h16)(p[5] * r)};
            u23.h[1] = (v2h){(h16)(p[6] * r), (h16)(p[7] * r)};
            u4.h     = (v2h){(h16)(p[8] * r), (h16)0.f};
            *(float2*)(row)      = u01.f;
            *(float2*)(row + 8)  = u23.f;
            *(float*)(row + 16)  = u4.f;
        }
        WAVE_SYNC();

        // ---- E2: h2 = att @ Wh2, in place into acc ----
        #pragma unroll
        for (int h = 0; h < 3; ++h) {
            float t0[9], t1[9];
            #pragma unroll
            for (int i = 0; i < 9; ++i) {
                const char* row = (const char*)(g + O_U) + (h * 9 + i) * 24;
                U2 a01, a23; U1 a4;
                a01.f = *(const float2*)row;
                a23.f = *(const float2*)(row + 8);
                a4.f  = *(const float*)(row + 16);
                float pj[9];
                pj[0] = (float)a01.h[0].x; pj[1] = (float)a01.h[0].y;
                pj[2] = (float)a01.h[1].x; pj[3] = (float)a01.h[1].y;
                pj[4] = (float)a23.h[0].x; pj[5] = (float)a23.h[0].y;
                pj[6] = (float)a23.h[1].x; pj[7] = (float)a23.h[1].y;
                pj[8] = (float)a4.h.x;
                float s0 = 0.f, s1 = 0.f;
                #pragma unroll
                for (int j = 0; j < 9; ++j) {
                    s0 += pj[j] * acc[j][2 * h];
                    s1 += pj[j] * acc[j][2 * h + 1];
                }
                t0[i] = s0; t1[i] = s1;
            }
            #pragma unroll
            for (int i = 0; i < 9; ++i) { acc[i][2 * h] = t0[i]; acc[i][2 * h + 1] = t1[i]; }
        }

        // ---- F0: pack h2 to f16 pair-slots in LDS (overlay at group base) ----
        #pragma unroll
        for (int n = 0; n < 9; ++n) {
            #pragma unroll
            for (int kp = 0; kp < 3; ++kp) {
                U1 u; u.h = (v2h){(h16)acc[n][2 * kp], (h16)acc[n][2 * kp + 1]};
                ((float*)g)[n * 24 + 3 * l8 + kp] = u.f;
            }
        }
        WAVE_SYNC();

        // ---- F+G: scores via dot2 against pre-packed Wp1; butterfly once per n ----
        float sp[9];
        #pragma unroll
        for (int n = 0; n < 9; ++n) sp[n] = 0.f;
        #pragma unroll
        for (int kk = 0; kk < 3; ++kk) {
            int k = l8 + 8 * kk;
            U4 w0, w1, w2u, w3, w4, w5;
            w0.f = wsf4[576 + k * 6 + 0];
            w1.f = wsf4[576 + k * 6 + 1];
            w2u.f = wsf4[576 + k * 6 + 2];
            w3.f = wsf4[576 + k * 6 + 3];
            w4.f = wsf4[576 + k * 6 + 4];
            w5.f = wsf4[576 + k * 6 + 5];
            #pragma unroll
            for (int n = 0; n < 9; ++n) {
                float a = 0.f;
                U4 x;
                x.f = h2f4[n * 6 + 0];
                a = FDOT2(x.h[0], w0.h[0], a); a = FDOT2(x.h[1], w0.h[1], a);
                a = FDOT2(x.h[2], w0.h[2], a); a = FDOT2(x.h[3], w0.h[3], a);
                x.f = h2f4[n * 6 + 1];
                a = FDOT2(x.h[0], w1.h[0], a); a = FDOT2(x.h[1], w1.h[1], a);
                a = FDOT2(x.h[2], w1.h[2], a); a = FDOT2(x.h[3], w1.h[3], a);
                x.f = h2f4[n * 6 + 2];
                a = FDOT2(x.h[0], w2u.h[0], a); a = FDOT2(x.h[1], w2u.h[1], a);
                a = FDOT2(x.h[2], w2u.h[2], a); a = FDOT2(x.h[3], w2u.h[3], a);
                x.f = h2f4[n * 6 + 3];
                a = FDOT2(x.h[0], w3.h[0], a); a = FDOT2(x.h[1], w3.h[1], a);
                a = FDOT2(x.h[2], w3.h[2], a); a = FDOT2(x.h[3], w3.h[3], a);
                x.f = h2f4[n * 6 + 4];
                a = FDOT2(x.h[0], w4.h[0], a); a = FDOT2(x.h[1], w4.h[1], a);
                a = FDOT2(x.h[2], w4.h[2], a); a = FDOT2(x.h[3], w4.h[3], a);
                x.f = h2f4[n * 6 + 5];
                a = FDOT2(x.h[0], w5.h[0], a); a = FDOT2(x.h[1], w5.h[1], a);
                a = FDOT2(x.h[2], w5.h[2], a); a = FDOT2(x.h[3], w5.h[3], a);
                float tv = tanh_fast(a + bq[kk]);
                sp[n] += tv * wq[kk];
            }
        }
        #pragma unroll
        for (int n = 0; n < 9; ++n) {
            sp[n] += __shfl_xor(sp[n], 1, 8);
            sp[n] += __shfl_xor(sp[n], 2, 8);
            sp[n] += __shfl_xor(sp[n], 4, 8);
        }

        // ---- H: node softmax (bp2 cancels) + weighted sum -> out ----
        float mx = sp[0];
        #pragma unroll
        for (int n = 1; n < 9; ++n) mx = fmaxf(mx, sp[n]);
        float wn9[9], sum = 0.f;
        #pragma unroll
        for (int n = 0; n < 9; ++n) { wn9[n] = __expf(sp[n] - mx); sum += wn9[n]; }
        float r = fast_rcp(sum);
        #pragma unroll
        for (int k = 0; k < 6; ++k) {
            float ov = 0.f;
            #pragma unroll
            for (int n = 0; n < 9; ++n) ov += wn9[n] * acc[n][k];
            out[(size_t)b * 48 + l8 + 8 * k] = ov * r;
        }
        WAVE_SYNC();
    }
}

extern "C" void kernel_launch(void* const* d_in, const int* in_sizes, int n_in,
                              void* d_out, int out_size, void* d_ws, size_t ws_size,
                              hipStream_t stream) {
    const float* obs = (const float*)d_in[0];
    const float* adj = (const float*)d_in[1];
    const float* W1  = (const float*)d_in[2];
    const float* a1  = (const float*)d_in[3];
    const float* W2  = (const float*)d_in[4];
    const float* a2  = (const float*)d_in[5];
    const float* Wp1 = (const float*)d_in[6];
    const float* bp1 = (const float*)d_in[7];
    const float* Wp2 = (const float*)d_in[8];
    float* out = (float*)d_out;
    h16* ws = (h16*)d_ws;

    const int B = in_sizes[0] / 9;

    prep_kernel<<<(48 * 96 + 576 + 255) / 256, 256, 0, stream>>>(W2, Wp1, ws);

    gnn_gat_kernel<<<4096, 128, 0, stream>>>(
        obs, adj, W1, a1, a2, bp1, Wp2, ws, out, B);
}

// Round 5
// 743.642 us; speedup vs baseline: 1.2023x; 1.2023x over previous
//
#include <hip/hip_runtime.h>
#include <math.h>

typedef _Float16 h16;
typedef _Float16 v2h __attribute__((ext_vector_type(2)));

#define ALPHA 0.2f
#define MASKV -9000000000000000.0f

constexpr int GSCR = 268;   // floats per group scratch slot
constexpr int O_S  = 0;     // s[27] f32
constexpr int O_F1 = 28;    // f1[27] f32
constexpr int O_F2 = 56;    // f2[3][10] f32
constexpr int O_U  = 92;    // byte 368 (16B aligned): h1 tile [9][32] f16 / att [27][12] f16
// h2 f16 [9][48] overlays floats [0,216) -- only live after att reads are done.

#if defined(__has_builtin)
#  if __has_builtin(__builtin_amdgcn_fdot2)
#    define FDOT2(a,b,c) __builtin_amdgcn_fdot2((a),(b),(c),false)
#  endif
#endif
#ifndef FDOT2
__device__ __forceinline__ float fdot2_sw(v2h a, v2h b, float c) {
    return c + (float)a.x*(float)b.x + (float)a.y*(float)b.y;
}
#  define FDOT2(a,b,c) fdot2_sw((a),(b),(c))
#endif

union U4 { float4 f; v2h h[4]; };
union U2 { float2 f; v2h h[2]; };
union U1 { float  f; v2h h;    };

#define WAVE_SYNC() asm volatile("s_waitcnt lgkmcnt(0)" ::: "memory")

__device__ __forceinline__ float fast_rcp(float x) { return __builtin_amdgcn_rcpf(x); }
__device__ __forceinline__ float tanh_fast(float x) {
    float e = __expf(x + x);
    return 1.f - 2.f * fast_rcp(e + 1.f);
}

// ws layout (halves): [0,4608): w2H[c][i] (48x96).  [4608,5760): wp1H[k][c] (24x48).
__global__ void prep_kernel(const float* __restrict__ W2, const float* __restrict__ Wp1,
                            h16* __restrict__ ws) {
    int t = blockIdx.x * 256 + threadIdx.x;
    if (t < 48 * 96) {
        int c = t / 96, i = t - c * 96;
        int h = c >> 4, d = c & 15;
        ws[t] = (h16)W2[(h * 96 + i) * 16 + d];
    } else if (t < 48 * 96 + 24 * 48) {
        int t2 = t - 48 * 96;
        int k = t2 / 48, c = t2 - k * 48;
        ws[t] = (h16)Wp1[c * 24 + k];
    }
}

// 16-lane groups (4 batches/wave): acc[9][3]=27 regs, true pressure ~80.
// waves_per_eu pinned (4,4): VGPR budget 128, scheduler can't chase 8-waves
// and re-introduce the spill that cost rounds 3/4 0.35-2.1 GB of scratch HBM.
__global__ __launch_bounds__(128) __attribute__((amdgpu_waves_per_eu(4, 4)))
void gnn_gat_kernel(
    const float* __restrict__ obs, const float* __restrict__ adj,
    const float* __restrict__ W1,  const float* __restrict__ a1,
    const float* __restrict__ a2,  const float* __restrict__ bp1,
    const float* __restrict__ Wp2, const h16* __restrict__ ws,
    float* __restrict__ out, int B)
{
    __shared__ float sW1[96];
    __shared__ float sAdj[81];
    __shared__ float sC12[6];
    __shared__ __align__(16) float smem[8 * GSCR];

    const int tid = threadIdx.x;
    if (tid < 96) sW1[tid] = W1[tid];
    if (tid < 81) sAdj[tid] = adj[tid];
    if (tid < 6) {
        int gg = tid >> 1, w = tid & 1;
        float s = 0.f;
        for (int d = 0; d < 32; ++d)
            s += W1[gg * 32 + d] * a1[gg * 64 + w * 32 + d];
        sC12[tid] = s;
    }
    __syncthreads();

    const int wv = tid >> 6, lane = tid & 63;
    const int q = lane >> 4, l16 = lane & 15;
    const int slot = wv * 4 + q;
    float* g = smem + slot * GSCR;
    float4* hUf4 = (float4*)(g + O_U);   // h1 tile: [9][4] float4 (f16x8 each)
    float4* h2f4 = (float4*)g;           // h2 f16 rows: [9][6] float4
    h16* gh = (h16*)g;                   // h2 half view
    const float4* wsf4 = (const float4*)ws;

    // per-lane constants
    float a2a[3], a2b[3];
    #pragma unroll
    for (int h = 0; h < 3; ++h) {
        a2a[h] = a2[h * 32 + l16];        // d = l16
        a2b[h] = a2[h * 32 + 16 + l16];
    }
    unsigned am[3];
    #pragma unroll
    for (int r = 0; r < 3; ++r) {
        unsigned u = 0;
        for (int t = 0; t < 27; ++t)
            u |= (sAdj[r * 27 + t] > 0.f ? 1u : 0u) << t;
        am[r] = u;
    }
    const int kB2 = 16 + (l16 & 7);
    float kw[2], kb[2];
    kw[0] = Wp2[l16];             kb[0] = bp1[l16];
    kw[1] = (l16 < 8) ? Wp2[kB2] : 0.f;
    kb[1] = bp1[kB2];

    const int stride = gridDim.x * 8;
    for (int b = blockIdx.x * 8 + slot; b < B; b += stride) {
        // ---- A: obs -> regs ----
        float o_r[9];
        #pragma unroll
        for (int j = 0; j < 9; ++j) o_r[j] = obs[(size_t)b * 9 + j];

        // ---- B: layer-1 collapsed attention -> s[g][n] ----
        #pragma unroll
        for (int it = 0; it < 2; ++it) {
            int t = l16 + 16 * it;
            if (t < 27) {
                int gg = (t >= 18) ? 2 : (t >= 9 ? 1 : 0);
                int n = t - 9 * gg;
                float f1 = sC12[2 * gg] * o_r[n];
                float c2 = sC12[2 * gg + 1];
                unsigned rbits = (am[n / 3] >> (9 * (n % 3))) & 0x1FFu;
                float e[9], m = -3.0e38f;
                #pragma unroll
                for (int j = 0; j < 9; ++j) {
                    float x = f1 + c2 * o_r[j];
                    x = x > 0.f ? x : ALPHA * x;
                    x = ((rbits >> j) & 1) ? x : MASKV;
                    e[j] = x; m = fmaxf(m, x);
                }
                float sum = 0.f, sw = 0.f;
                #pragma unroll
                for (int j = 0; j < 9; ++j) {
                    float p = __expf(e[j] - m);
                    sum += p; sw += p * o_r[j];
                }
                g[O_S + t] = sw * fast_rcp(sum);
            }
        }
        WAVE_SYNC();

        // ---- C/D: 3 K-tiles of 32; h1 f16 in LDS, GEMM via v_dot2 ----
        float acc[9][3];
        #pragma unroll
        for (int n = 0; n < 9; ++n)
            #pragma unroll
            for (int h = 0; h < 3; ++h) acc[n][h] = 0.f;

        for (int p = 0; p < 3; ++p) {
            // C: h1[n][0..31] = elu(s[p][n] * W1[32p..32p+31]) as f16
            #pragma unroll
            for (int it = 0; it < 3; ++it) {
                int t = l16 + 16 * it;
                if (t < 36) {
                    int n = t >> 2, ib = t & 3;
                    int i0 = 32 * p + 8 * ib;
                    float sv = g[O_S + p * 9 + n];
                    float4 wa = *(const float4*)&sW1[i0];
                    float4 wb = *(const float4*)&sW1[i0 + 4];
                    float v0 = sv * wa.x, v1 = sv * wa.y, v2 = sv * wa.z, v3 = sv * wa.w;
                    float v4 = sv * wb.x, v5 = sv * wb.y, v6 = sv * wb.z, v7 = sv * wb.w;
                    v0 = v0 > 0.f ? v0 : __expf(v0) - 1.f;
                    v1 = v1 > 0.f ? v1 : __expf(v1) - 1.f;
                    v2 = v2 > 0.f ? v2 : __expf(v2) - 1.f;
                    v3 = v3 > 0.f ? v3 : __expf(v3) - 1.f;
                    v4 = v4 > 0.f ? v4 : __expf(v4) - 1.f;
                    v5 = v5 > 0.f ? v5 : __expf(v5) - 1.f;
                    v6 = v6 > 0.f ? v6 : __expf(v6) - 1.f;
                    v7 = v7 > 0.f ? v7 : __expf(v7) - 1.f;
                    U4 u;
                    u.h[0] = (v2h){(h16)v0, (h16)v1};
                    u.h[1] = (v2h){(h16)v2, (h16)v3};
                    u.h[2] = (v2h){(h16)v4, (h16)v5};
                    u.h[3] = (v2h){(h16)v6, (h16)v7};
                    hUf4[n * 4 + ib] = u.f;
                }
            }
            WAVE_SYNC();

            // D: acc[n][h] += h1[n][i:i+8] . w2[c=l16+16h][i:i+8]
            #pragma unroll
            for (int ib = 0; ib < 4; ++ib) {
                U4 w[3];
                #pragma unroll
                for (int h = 0; h < 3; ++h)
                    w[h].f = wsf4[(l16 + 16 * h) * 12 + p * 4 + ib];
                #pragma unroll
                for (int n = 0; n < 9; ++n) {
                    U4 hh; hh.f = hUf4[n * 4 + ib];
                    #pragma unroll
                    for (int h = 0; h < 3; ++h) {
                        float a = acc[n][h];
                        a = FDOT2(hh.h[0], w[h].h[0], a);
                        a = FDOT2(hh.h[1], w[h].h[1], a);
                        a = FDOT2(hh.h[2], w[h].h[2], a);
                        a = FDOT2(hh.h[3], w[h].h[3], a);
                        acc[n][h] = a;
                    }
                }
            }
            WAVE_SYNC();
        }

        // ---- f1/f2 for layer-2 attention (butterfly over the 16 d-lanes) ----
        #pragma unroll
        for (int h = 0; h < 3; ++h) {
            #pragma unroll
            for (int n = 0; n < 9; ++n) {
                float v1 = acc[n][h] * a2a[h];
                float v2 = acc[n][h] * a2b[h];
                v1 += __shfl_xor(v1, 1, 16); v2 += __shfl_xor(v2, 1, 16);
                v1 += __shfl_xor(v1, 2, 16); v2 += __shfl_xor(v2, 2, 16);
                v1 += __shfl_xor(v1, 4, 16); v2 += __shfl_xor(v2, 4, 16);
                v1 += __shfl_xor(v1, 8, 16); v2 += __shfl_xor(v2, 8, 16);
                if (((h * 9 + n) & 15) == l16) {
                    g[O_F1 + h * 9 + n]  = v1;
                    g[O_F2 + h * 10 + n] = v2;
                }
            }
        }
        WAVE_SYNC();

        // ---- E1: att rows -> f16 LDS [27][12] ----
        #pragma unroll
        for (int it = 0; it < 2; ++it) {
            int t = l16 + 16 * it;
            if (t < 27) {
                int h = (t >= 18) ? 2 : (t >= 9 ? 1 : 0);
                int i = t - 9 * h;
                float f1i = g[O_F1 + t];
                float f2r[9];
                #pragma unroll
                for (int j = 0; j < 9; ++j) f2r[j] = g[O_F2 + h * 10 + j];
                unsigned rbits = (am[i / 3] >> (9 * (i % 3))) & 0x1FFu;
                float e[9], m = -3.0e38f;
                #pragma unroll
                for (int j = 0; j < 9; ++j) {
                    float x = f1i + f2r[j];
                    x = x > 0.f ? x : ALPHA * x;
                    x = ((rbits >> j) & 1) ? x : MASKV;
                    e[j] = x; m = fmaxf(m, x);
                }
                float p[9], sum = 0.f;
                #pragma unroll
                for (int j = 0; j < 9; ++j) { p[j] = __expf(e[j] - m); sum += p[j]; }
                float r = fast_rcp(sum);
                char* row = (char*)(g + O_U) + t * 24;
                U2 u01, u23; U1 u4;
                u01.h[0] = (v2h){(h16)(p[0] * r), (h16)(p[1] * r)};
                u01.h[1] = (v2h){(h16)(p[2] * r), (h16)(p[3] * r)};
                u23.h[0] = (v2h){(h16)(p[4] * r), (h16)(p[5] * r)};
                u23.h[1] = (v2h){(h16)(p[6] * r), (h16)(p[7] * r)};
                u4.h     = (v2h){(h16)(p[8] * r), (h16)0.f};
                *(float2*)(row)      = u01.f;
                *(float2*)(row + 8)  = u23.f;
                *(float*)(row + 16)  = u4.f;
            }
        }
        WAVE_SYNC();

        // ---- E2: h2 = att @ Wh2, in place into acc (one column per head per lane) ----
        #pragma unroll
        for (int h = 0; h < 3; ++h) {
            float t0[9];
            #pragma unroll
            for (int i = 0; i < 9; ++i) {
                const char* row = (const char*)(g + O_U) + (h * 9 + i) * 24;
                U2 a01, a23; U1 a4;
                a01.f = *(const float2*)row;
                a23.f = *(const float2*)(row + 8);
                a4.f  = *(const float*)(row + 16);
                t0[i] = (float)a01.h[0].x * acc[0][h] + (float)a01.h[0].y * acc[1][h]
                      + (float)a01.h[1].x * acc[2][h] + (float)a01.h[1].y * acc[3][h]
                      + (float)a23.h[0].x * acc[4][h] + (float)a23.h[0].y * acc[5][h]
                      + (float)a23.h[1].x * acc[6][h] + (float)a23.h[1].y * acc[7][h]
                      + (float)a4.h.x * acc[8][h];
            }
            #pragma unroll
            for (int i = 0; i < 9; ++i) acc[i][h] = t0[i];
        }
        WAVE_SYNC();

        // ---- F0: pack h2 -> f16 rows [9][48] at group base ----
        #pragma unroll
        for (int n = 0; n < 9; ++n)
            #pragma unroll
            for (int h = 0; h < 3; ++h)
                gh[n * 48 + l16 + 16 * h] = (h16)acc[n][h];
        WAVE_SYNC();

        // ---- F+G: scores = tanh(h2 @ Wp1 + bp1) @ Wp2 (butterfly over 16 lanes) ----
        float sp[9];
        #pragma unroll
        for (int n = 0; n < 9; ++n) sp[n] = 0.f;
        #pragma unroll
        for (int kk = 0; kk < 2; ++kk) {
            int k = (kk == 0) ? l16 : kB2;
            U4 w[6];
            #pragma unroll
            for (int j = 0; j < 6; ++j)
                w[j].f = wsf4[576 + k * 6 + j];
            #pragma unroll
            for (int n = 0; n < 9; ++n) {
                float a = 0.f;
                #pragma unroll
                for (int j = 0; j < 6; ++j) {
                    U4 x; x.f = h2f4[n * 6 + j];
                    a = FDOT2(x.h[0], w[j].h[0], a);
                    a = FDOT2(x.h[1], w[j].h[1], a);
                    a = FDOT2(x.h[2], w[j].h[2], a);
                    a = FDOT2(x.h[3], w[j].h[3], a);
                }
                float tv = tanh_fast(a + kb[kk]);
                sp[n] += tv * kw[kk];
            }
        }
        #pragma unroll
        for (int n = 0; n < 9; ++n) {
            sp[n] += __shfl_xor(sp[n], 1, 16);
            sp[n] += __shfl_xor(sp[n], 2, 16);
            sp[n] += __shfl_xor(sp[n], 4, 16);
            sp[n] += __shfl_xor(sp[n], 8, 16);
        }

        // ---- H: node softmax (bp2 cancels) + weighted sum -> out ----
        float mx = sp[0];
        #pragma unroll
        for (int n = 1; n < 9; ++n) mx = fmaxf(mx, sp[n]);
        float wn9[9], sum = 0.f;
        #pragma unroll
        for (int n = 0; n < 9; ++n) { wn9[n] = __expf(sp[n] - mx); sum += wn9[n]; }
        float r = fast_rcp(sum);
        #pragma unroll
        for (int h = 0; h < 3; ++h) {
            float ov = 0.f;
            #pragma unroll
            for (int n = 0; n < 9; ++n) ov += wn9[n] * acc[n][h];
            out[(size_t)b * 48 + l16 + 16 * h] = ov * r;
        }
        WAVE_SYNC();
    }
}

extern "C" void kernel_launch(void* const* d_in, const int* in_sizes, int n_in,
                              void* d_out, int out_size, void* d_ws, size_t ws_size,
                              hipStream_t stream) {
    const float* obs = (const float*)d_in[0];
    const float* adj = (const float*)d_in[1];
    const float* W1  = (const float*)d_in[2];
    const float* a1  = (const float*)d_in[3];
    const float* W2  = (const float*)d_in[4];
    const float* a2  = (const float*)d_in[5];
    const float* Wp1 = (const float*)d_in[6];
    const float* bp1 = (const float*)d_in[7];
    const float* Wp2 = (const float*)d_in[8];
    float* out = (float*)d_out;
    h16* ws = (h16*)d_ws;

    const int B = in_sizes[0] / 9;

    prep_kernel<<<(48 * 96 + 24 * 48 + 255) / 256, 256, 0, stream>>>(W2, Wp1, ws);

    // 4096 blocks x 8 group-slots = 32768 slots -> 4 batches/slot at B=131072
    gnn_gat_kernel<<<4096, 128, 0, stream>>>(
        obs, adj, W1, a1, a2, bp1, Wp2, ws, out, B);
}

// Round 6
// 699.215 us; speedup vs baseline: 1.2787x; 1.0635x over previous
//
#include <hip/hip_runtime.h>
#include <math.h>

typedef _Float16 h16;
typedef _Float16 v2h __attribute__((ext_vector_type(2)));

#define ALPHA 0.2f
#define MASKV -9000000000000000.0f

constexpr int GSCR = 268;   // floats per group scratch slot (268 mod 32 = 12 -> slots tile banks)
constexpr int O_S  = 0;     // s[27] f32
constexpr int O_F1 = 28;    // f1[27] f32
constexpr int O_F2 = 56;    // f2[3][10] f32
constexpr int O_U  = 92;    // byte 368: h1 tile [9][32] f16 / att [27][12] f16
// h2 f16 [9][48] overlays floats [0,216) -- only live after att reads are done.

constexpr int W2P = 104;    // sW2h pitch in halves (52 dwords: gcd(52,32)=4 -> 2-way, free)
constexpr int WPP = 56;     // sWp1h pitch in halves (28 dwords: 2-way, free)

#if defined(__has_builtin)
#  if __has_builtin(__builtin_amdgcn_fdot2)
#    define FDOT2(a,b,c) __builtin_amdgcn_fdot2((a),(b),(c),false)
#  endif
#endif
#ifndef FDOT2
__device__ __forceinline__ float fdot2_sw(v2h a, v2h b, float c) {
    return c + (float)a.x*(float)b.x + (float)a.y*(float)b.y;
}
#  define FDOT2(a,b,c) fdot2_sw((a),(b),(c))
#endif

union U4 { float4 f; v2h h[4]; };
union U2 { float2 f; v2h h[2]; };
union U1 { float  f; v2h h;    };

#define WAVE_SYNC() asm volatile("s_waitcnt lgkmcnt(0)" ::: "memory")

__device__ __forceinline__ float fast_rcp(float x) { return __builtin_amdgcn_rcpf(x); }
__device__ __forceinline__ float tanh_fast(float x) {
    float e = __expf(x + x);
    return 1.f - 2.f * fast_rcp(e + 1.f);
}

// ws layout (halves): [0,4608): w2t[c][i] (48x96).  [4608,5760): wp1[k][c] (24x48).
__global__ void prep_kernel(const float* __restrict__ W2, const float* __restrict__ Wp1,
                            h16* __restrict__ ws) {
    int t = blockIdx.x * 256 + threadIdx.x;
    if (t < 48 * 96) {
        int c = t / 96, i = t - c * 96;
        int h = c >> 4, d = c & 15;
        ws[t] = (h16)W2[(h * 96 + i) * 16 + d];
    } else if (t < 48 * 96 + 24 * 48) {
        int t2 = t - 48 * 96;
        int k = t2 / 48, c = t2 - k * 48;
        ws[t] = (h16)Wp1[c * 24 + k];
    }
}

// Weights live in LDS: ds_reads can't be LICM-hoisted past the loop's ds_writes,
// which is what made rounds 3-5 spill 0.3-2 GB (global weight loads hoisted ->
// ~190 hoisted VGPRs -> spill). Round 2 (weights in LDS) had FETCH = 3.4 MB.
__global__ __launch_bounds__(128, 3)
void gnn_gat_kernel(
    const float* __restrict__ obs, const float* __restrict__ adj,
    const float* __restrict__ W1,  const float* __restrict__ a1,
    const float* __restrict__ a2,  const float* __restrict__ bp1,
    const float* __restrict__ Wp2, const h16* __restrict__ ws,
    float* __restrict__ out, int B)
{
    __shared__ float sW1[96];
    __shared__ float sAdj[81];
    __shared__ float sC12[6];
    __shared__ __align__(16) h16 sW2h[48 * W2P];   // [c][i], pitch 104
    __shared__ __align__(16) h16 sWp1h[24 * WPP];  // [k][c], pitch 56
    __shared__ __align__(16) float smem[8 * GSCR];

    const int tid = threadIdx.x;
    if (tid < 96) sW1[tid] = W1[tid];
    if (tid < 81) sAdj[tid] = adj[tid];
    if (tid < 6) {
        int gg = tid >> 1, w = tid & 1;
        float s = 0.f;
        for (int d = 0; d < 32; ++d)
            s += W1[gg * 32 + d] * a1[gg * 64 + w * 32 + d];
        sC12[tid] = s;
    }
    for (int t = tid; t < 48 * 96; t += 128) {
        int c = t / 96, i = t - c * 96;
        sW2h[c * W2P + i] = ws[t];
    }
    for (int t = tid; t < 24 * 48; t += 128) {
        int k = t / 48, c = t - k * 48;
        sWp1h[k * WPP + c] = ws[4608 + t];
    }
    __syncthreads();

    const int wv = tid >> 6, lane = tid & 63;
    const int q = lane >> 4, l16 = lane & 15;
    const int slot = wv * 4 + q;
    float* g = smem + slot * GSCR;
    float4* hUf4 = (float4*)(g + O_U);   // h1 tile: [9][4] float4 (f16x8 each)
    float4* h2f4 = (float4*)g;           // h2 f16 rows: [9][6] float4
    h16* gh = (h16*)g;                   // h2 half view
    const float4* sW2f4  = (const float4*)sW2h;   // pitch 13 float4 per c
    const float4* sWp1f4 = (const float4*)sWp1h;  // pitch 7 float4 per k

    // per-lane constants
    float a2a[3], a2b[3];
    #pragma unroll
    for (int h = 0; h < 3; ++h) {
        a2a[h] = a2[h * 32 + l16];        // d = l16
        a2b[h] = a2[h * 32 + 16 + l16];
    }
    unsigned am[3];
    #pragma unroll
    for (int r = 0; r < 3; ++r) {
        unsigned u = 0;
        for (int t = 0; t < 27; ++t)
            u |= (sAdj[r * 27 + t] > 0.f ? 1u : 0u) << t;
        am[r] = u;
    }
    const int kB2 = 16 + (l16 & 7);
    float kw[2], kb[2];
    kw[0] = Wp2[l16];             kb[0] = bp1[l16];
    kw[1] = (l16 < 8) ? Wp2[kB2] : 0.f;
    kb[1] = bp1[kB2];

    const int stride = gridDim.x * 8;
    for (int b = blockIdx.x * 8 + slot; b < B; b += stride) {
        // ---- A: obs -> regs ----
        float o_r[9];
        #pragma unroll
        for (int j = 0; j < 9; ++j) o_r[j] = obs[(size_t)b * 9 + j];

        // ---- B: layer-1 collapsed attention -> s[g][n] ----
        #pragma unroll
        for (int it = 0; it < 2; ++it) {
            int t = l16 + 16 * it;
            if (t < 27) {
                int gg = (t >= 18) ? 2 : (t >= 9 ? 1 : 0);
                int n = t - 9 * gg;
                float f1 = sC12[2 * gg] * o_r[n];
                float c2 = sC12[2 * gg + 1];
                unsigned rbits = (am[n / 3] >> (9 * (n % 3))) & 0x1FFu;
                float e[9], m = -3.0e38f;
                #pragma unroll
                for (int j = 0; j < 9; ++j) {
                    float x = f1 + c2 * o_r[j];
                    x = x > 0.f ? x : ALPHA * x;
                    x = ((rbits >> j) & 1) ? x : MASKV;
                    e[j] = x; m = fmaxf(m, x);
                }
                float sum = 0.f, sw = 0.f;
                #pragma unroll
                for (int j = 0; j < 9; ++j) {
                    float p = __expf(e[j] - m);
                    sum += p; sw += p * o_r[j];
                }
                g[O_S + t] = sw * fast_rcp(sum);
            }
        }
        WAVE_SYNC();

        // ---- C/D: 3 K-tiles of 32; h1 f16 in LDS, GEMM via v_dot2 ----
        float acc[9][3];
        #pragma unroll
        for (int n = 0; n < 9; ++n)
            #pragma unroll
            for (int h = 0; h < 3; ++h) acc[n][h] = 0.f;

        for (int p = 0; p < 3; ++p) {
            // C: h1[n][0..31] = elu(s[p][n] * W1[32p..32p+31]) as f16
            #pragma unroll
            for (int it = 0; it < 3; ++it) {
                int t = l16 + 16 * it;
                if (t < 36) {
                    int n = t >> 2, ib = t & 3;
                    int i0 = 32 * p + 8 * ib;
                    float sv = g[O_S + p * 9 + n];
                    float4 wa = *(const float4*)&sW1[i0];
                    float4 wb = *(const float4*)&sW1[i0 + 4];
                    float v0 = sv * wa.x, v1 = sv * wa.y, v2 = sv * wa.z, v3 = sv * wa.w;
                    float v4 = sv * wb.x, v5 = sv * wb.y, v6 = sv * wb.z, v7 = sv * wb.w;
                    v0 = v0 > 0.f ? v0 : __expf(v0) - 1.f;
                    v1 = v1 > 0.f ? v1 : __expf(v1) - 1.f;
                    v2 = v2 > 0.f ? v2 : __expf(v2) - 1.f;
                    v3 = v3 > 0.f ? v3 : __expf(v3) - 1.f;
                    v4 = v4 > 0.f ? v4 : __expf(v4) - 1.f;
                    v5 = v5 > 0.f ? v5 : __expf(v5) - 1.f;
                    v6 = v6 > 0.f ? v6 : __expf(v6) - 1.f;
                    v7 = v7 > 0.f ? v7 : __expf(v7) - 1.f;
                    U4 u;
                    u.h[0] = (v2h){(h16)v0, (h16)v1};
                    u.h[1] = (v2h){(h16)v2, (h16)v3};
                    u.h[2] = (v2h){(h16)v4, (h16)v5};
                    u.h[3] = (v2h){(h16)v6, (h16)v7};
                    hUf4[n * 4 + ib] = u.f;
                }
            }
            WAVE_SYNC();

            // D: acc[n][h] += h1[n][i:i+8] . w2[c=l16+16h][i:i+8]  (weights from LDS)
            #pragma unroll
            for (int ib = 0; ib < 4; ++ib) {
                U4 w[3];
                #pragma unroll
                for (int h = 0; h < 3; ++h)
                    w[h].f = sW2f4[(l16 + 16 * h) * 13 + p * 4 + ib];
                #pragma unroll
                for (int n = 0; n < 9; ++n) {
                    U4 hh; hh.f = hUf4[n * 4 + ib];
                    #pragma unroll
                    for (int h = 0; h < 3; ++h) {
                        float a = acc[n][h];
                        a = FDOT2(hh.h[0], w[h].h[0], a);
                        a = FDOT2(hh.h[1], w[h].h[1], a);
                        a = FDOT2(hh.h[2], w[h].h[2], a);
                        a = FDOT2(hh.h[3], w[h].h[3], a);
                        acc[n][h] = a;
                    }
                }
            }
            WAVE_SYNC();
        }

        // ---- f1/f2 for layer-2 attention (butterfly over the 16 d-lanes) ----
        #pragma unroll
        for (int h = 0; h < 3; ++h) {
            #pragma unroll
            for (int n = 0; n < 9; ++n) {
                float v1 = acc[n][h] * a2a[h];
                float v2 = acc[n][h] * a2b[h];
                v1 += __shfl_xor(v1, 1, 16); v2 += __shfl_xor(v2, 1, 16);
                v1 += __shfl_xor(v1, 2, 16); v2 += __shfl_xor(v2, 2, 16);
                v1 += __shfl_xor(v1, 4, 16); v2 += __shfl_xor(v2, 4, 16);
                v1 += __shfl_xor(v1, 8, 16); v2 += __shfl_xor(v2, 8, 16);
                if (((h * 9 + n) & 15) == l16) {
                    g[O_F1 + h * 9 + n]  = v1;
                    g[O_F2 + h * 10 + n] = v2;
                }
            }
        }
        WAVE_SYNC();

        // ---- E1: att rows -> f16 LDS [27][12] ----
        #pragma unroll
        for (int it = 0; it < 2; ++it) {
            int t = l16 + 16 * it;
            if (t < 27) {
                int h = (t >= 18) ? 2 : (t >= 9 ? 1 : 0);
                int i = t - 9 * h;
                float f1i = g[O_F1 + t];
                float f2r[9];
                #pragma unroll
                for (int j = 0; j < 9; ++j) f2r[j] = g[O_F2 + h * 10 + j];
                unsigned rbits = (am[i / 3] >> (9 * (i % 3))) & 0x1FFu;
                float e[9], m = -3.0e38f;
                #pragma unroll
                for (int j = 0; j < 9; ++j) {
                    float x = f1i + f2r[j];
                    x = x > 0.f ? x : ALPHA * x;
                    x = ((rbits >> j) & 1) ? x : MASKV;
                    e[j] = x; m = fmaxf(m, x);
                }
                float p[9], sum = 0.f;
                #pragma unroll
                for (int j = 0; j < 9; ++j) { p[j] = __expf(e[j] - m); sum += p[j]; }
                float r = fast_rcp(sum);
                char* row = (char*)(g + O_U) + t * 24;
                U2 u01, u23; U1 u4;
                u01.h[0] = (v2h){(h16)(p[0] * r), (h16)(p[1] * r)};
                u01.h[1] = (v2h){(h16)(p[2] * r), (h16)(p[3] * r)};
                u23.h[0] = (v2h){(h16)(p[4] * r), (h16)(p[5] * r)};
                u23.h[1] = (v2h){(h16)(p[6] * r), (h16)(p[7] * r)};
                u4.h     = (v2h){(h16)(p[8] * r), (h16)0.f};
                *(float2*)(row)      = u01.f;
                *(float2*)(row + 8)  = u23.f;
                *(float*)(row + 16)  = u4.f;
            }
        }
        WAVE_SYNC();

        // ---- E2: h2 = att @ Wh2, in place into acc (one column per head per lane) ----
        #pragma unroll
        for (int h = 0; h < 3; ++h) {
            float t0[9];
            #pragma unroll
            for (int i = 0; i < 9; ++i) {
                const char* row = (const char*)(g + O_U) + (h * 9 + i) * 24;
                U2 a01, a23; U1 a4;
                a01.f = *(const float2*)row;
                a23.f = *(const float2*)(row + 8);
                a4.f  = *(const float*)(row + 16);
                t0[i] = (float)a01.h[0].x * acc[0][h] + (float)a01.h[0].y * acc[1][h]
                      + (float)a01.h[1].x * acc[2][h] + (float)a01.h[1].y * acc[3][h]
                      + (float)a23.h[0].x * acc[4][h] + (float)a23.h[0].y * acc[5][h]
                      + (float)a23.h[1].x * acc[6][h] + (float)a23.h[1].y * acc[7][h]
                      + (float)a4.h.x * acc[8][h];
            }
            #pragma unroll
            for (int i = 0; i < 9; ++i) acc[i][h] = t0[i];
        }
        WAVE_SYNC();

        // ---- F0: pack h2 -> f16 rows [9][48] at group base ----
        #pragma unroll
        for (int n = 0; n < 9; ++n)
            #pragma unroll
            for (int h = 0; h < 3; ++h)
                gh[n * 48 + l16 + 16 * h] = (h16)acc[n][h];
        WAVE_SYNC();

        // ---- F+G: scores = tanh(h2 @ Wp1 + bp1) @ Wp2 (butterfly over 16 lanes) ----
        float sp[9];
        #pragma unroll
        for (int n = 0; n < 9; ++n) sp[n] = 0.f;
        #pragma unroll
        for (int kk = 0; kk < 2; ++kk) {
            int k = (kk == 0) ? l16 : kB2;
            U4 w[6];
            #pragma unroll
            for (int j = 0; j < 6; ++j)
                w[j].f = sWp1f4[k * 7 + j];
            #pragma unroll
            for (int n = 0; n < 9; ++n) {
                float a = 0.f;
                #pragma unroll
                for (int j = 0; j < 6; ++j) {
                    U4 x; x.f = h2f4[n * 6 + j];
                    a = FDOT2(x.h[0], w[j].h[0], a);
                    a = FDOT2(x.h[1], w[j].h[1], a);
                    a = FDOT2(x.h[2], w[j].h[2], a);
                    a = FDOT2(x.h[3], w[j].h[3], a);
                }
                float tv = tanh_fast(a + kb[kk]);
                sp[n] += tv * kw[kk];
            }
        }
        #pragma unroll
        for (int n = 0; n < 9; ++n) {
            sp[n] += __shfl_xor(sp[n], 1, 16);
            sp[n] += __shfl_xor(sp[n], 2, 16);
            sp[n] += __shfl_xor(sp[n], 4, 16);
            sp[n] += __shfl_xor(sp[n], 8, 16);
        }

        // ---- H: node softmax (bp2 cancels) + weighted sum -> out ----
        float mx = sp[0];
        #pragma unroll
        for (int n = 1; n < 9; ++n) mx = fmaxf(mx, sp[n]);
        float wn9[9], sum = 0.f;
        #pragma unroll
        for (int n = 0; n < 9; ++n) { wn9[n] = __expf(sp[n] - mx); sum += wn9[n]; }
        float r = fast_rcp(sum);
        #pragma unroll
        for (int h = 0; h < 3; ++h) {
            float ov = 0.f;
            #pragma unroll
            for (int n = 0; n < 9; ++n) ov += wn9[n] * acc[n][h];
            out[(size_t)b * 48 + l16 + 16 * h] = ov * r;
        }
        WAVE_SYNC();
    }
}

extern "C" void kernel_launch(void* const* d_in, const int* in_sizes, int n_in,
                              void* d_out, int out_size, void* d_ws, size_t ws_size,
                              hipStream_t stream) {
    const float* obs = (const float*)d_in[0];
    const float* adj = (const float*)d_in[1];
    const float* W1  = (const float*)d_in[2];
    const float* a1  = (const float*)d_in[3];
    const float* W2  = (const float*)d_in[4];
    const float* a2  = (const float*)d_in[5];
    const float* Wp1 = (const float*)d_in[6];
    const float* bp1 = (const float*)d_in[7];
    const float* Wp2 = (const float*)d_in[8];
    float* out = (float*)d_out;
    h16* ws = (h16*)d_ws;

    const int B = in_sizes[0] / 9;

    prep_kernel<<<(48 * 96 + 24 * 48 + 255) / 256, 256, 0, stream>>>(W2, Wp1, ws);

    // 4096 blocks x 8 group-slots = 32768 slots -> 4 batches/slot at B=131072
    gnn_gat_kernel<<<4096, 128, 0, stream>>>(
        obs, adj, W1, a1, a2, bp1, Wp2, ws, out, B);
}

// Round 7
// 660.462 us; speedup vs baseline: 1.3537x; 1.0587x over previous
//
#include <hip/hip_runtime.h>
#include <math.h>

typedef _Float16 h16;
typedef _Float16 v2h __attribute__((ext_vector_type(2)));
typedef _Float16 v8h __attribute__((ext_vector_type(8)));

#define ALPHA 0.2f
#define MASKV -9000000000000000.0f

constexpr int GSCR = 268;   // floats per group scratch slot
constexpr int O_S  = 0;     // s[27] f32
constexpr int O_F1 = 28;    // f1[27] f32
constexpr int O_F2 = 56;    // f2[3][10] f32
constexpr int O_U  = 92;    // byte 368: h1 tile [9][32] f16 / att [27][12] f16
// h2 f16 [9][48] overlays floats [0,216) -- only live after att reads are done.

constexpr int W2P = 104;    // sW2h pitch in halves
constexpr int WPP = 56;     // sWp1h pitch in halves

#define FDOT2(a,b,c) __builtin_amdgcn_fdot2((a),(b),(c),false)

#define WAVE_SYNC() asm volatile("s_waitcnt lgkmcnt(0)" ::: "memory")

__device__ __forceinline__ float fast_rcp(float x) { return __builtin_amdgcn_rcpf(x); }
__device__ __forceinline__ float tanh_fast(float x) {
    float e = __expf(x + x);
    return 1.f - 2.f * fast_rcp(e + 1.f);
}
__device__ __forceinline__ float dot8(v8h x, v8h w, float a) {
    a = FDOT2(__builtin_shufflevector(x, x, 0, 1), __builtin_shufflevector(w, w, 0, 1), a);
    a = FDOT2(__builtin_shufflevector(x, x, 2, 3), __builtin_shufflevector(w, w, 2, 3), a);
    a = FDOT2(__builtin_shufflevector(x, x, 4, 5), __builtin_shufflevector(w, w, 4, 5), a);
    a = FDOT2(__builtin_shufflevector(x, x, 6, 7), __builtin_shufflevector(w, w, 6, 7), a);
    return a;
}
// adjacency row bits without any stack array (runtime shift is a VALU op)
__device__ __forceinline__ unsigned rowbits(unsigned a0, unsigned a1, unsigned a2, int n) {
    int nd = (n >= 6) ? 2 : ((n >= 3) ? 1 : 0);
    unsigned base = (nd == 0) ? a0 : ((nd == 1) ? a1 : a2);
    return (base >> (9 * (n - 3 * nd))) & 0x1FFu;
}

// ws layout (halves): [0,4608): w2t[c][i] (48x96).  [4608,5760): wp1[k][c] (24x48).
__global__ void prep_kernel(const float* __restrict__ W2, const float* __restrict__ Wp1,
                            h16* __restrict__ ws) {
    int t = blockIdx.x * 256 + threadIdx.x;
    if (t < 48 * 96) {
        int c = t / 96, i = t - c * 96;
        int h = c >> 4, d = c & 15;
        ws[t] = (h16)W2[(h * 96 + i) * 16 + d];
    } else if (t < 48 * 96 + 24 * 48) {
        int t2 = t - 48 * 96;
        int k = t2 / 48, c = t2 - k * 48;
        ws[t] = (h16)Wp1[c * 24 + k];
    }
}

// Zero stack objects: no unions, no runtime-indexed private arrays. The
// asm-"memory" wave syncs then have nothing to flush (rounds 3-6 lost
// 0.3-1.8 GB of HBM to scratch flush/reload of allocas across 8 syncs/batch).
__global__ __launch_bounds__(128, 3)
void gnn_gat_kernel(
    const float* __restrict__ obs, const float* __restrict__ adj,
    const float* __restrict__ W1,  const float* __restrict__ a1,
    const float* __restrict__ a2,  const float* __restrict__ bp1,
    const float* __restrict__ Wp2, const h16* __restrict__ ws,
    float* __restrict__ out, int B)
{
    __shared__ float sW1[96];
    __shared__ float sAdj[81];
    __shared__ float sC12[6];
    __shared__ __align__(16) h16 sW2h[48 * W2P];   // [c][i], pitch 104
    __shared__ __align__(16) h16 sWp1h[24 * WPP];  // [k][c], pitch 56
    __shared__ __align__(16) float smem[8 * GSCR];

    const int tid = threadIdx.x;
    if (tid < 96) sW1[tid] = W1[tid];
    if (tid < 81) sAdj[tid] = adj[tid];
    if (tid < 6) {
        int gg = tid >> 1, w = tid & 1;
        float s = 0.f;
        for (int d = 0; d < 32; ++d)
            s += W1[gg * 32 + d] * a1[gg * 64 + w * 32 + d];
        sC12[tid] = s;
    }
    for (int t = tid; t < 48 * 96; t += 128) {
        int c = t / 96, i = t - c * 96;
        sW2h[c * W2P + i] = ws[t];
    }
    for (int t = tid; t < 24 * 48; t += 128) {
        int k = t / 48, c = t - k * 48;
        sWp1h[k * WPP + c] = ws[4608 + t];
    }
    __syncthreads();

    const int wv = tid >> 6, lane = tid & 63;
    const int q = lane >> 4, l16 = lane & 15;
    const int slot = wv * 4 + q;
    float* g = smem + slot * GSCR;
    h16* hU = (h16*)(g + O_U);           // h1 tile [9][32] halves / att rows [27][12]
    h16* gh = (h16*)g;                   // h2 halves [9][48]

    // per-lane constants (all scalars / constant-indexed)
    float a2a0 = a2[l16],      a2b0 = a2[16 + l16];
    float a2a1 = a2[32 + l16], a2b1 = a2[48 + l16];
    float a2a2 = a2[64 + l16], a2b2 = a2[80 + l16];
    unsigned am0 = 0, am1 = 0, am2 = 0;
    for (int t = 0; t < 27; ++t) {
        if (sAdj[t]      > 0.f) am0 |= 1u << t;
        if (sAdj[27 + t] > 0.f) am1 |= 1u << t;
        if (sAdj[54 + t] > 0.f) am2 |= 1u << t;
    }
    const int kB2 = 16 + (l16 & 7);
    const float kw0 = Wp2[l16], kb0 = bp1[l16];
    const float kw1 = (l16 < 8) ? Wp2[kB2] : 0.f;
    const float kb1 = bp1[kB2];

    const int stride = gridDim.x * 8;
    for (int b = blockIdx.x * 8 + slot; b < B; b += stride) {
        // ---- A: obs -> regs ----
        float o0 = obs[(size_t)b * 9 + 0], o1 = obs[(size_t)b * 9 + 1];
        float o2 = obs[(size_t)b * 9 + 2], o3 = obs[(size_t)b * 9 + 3];
        float o4 = obs[(size_t)b * 9 + 4], o5 = obs[(size_t)b * 9 + 5];
        float o6 = obs[(size_t)b * 9 + 6], o7 = obs[(size_t)b * 9 + 7];
        float o8 = obs[(size_t)b * 9 + 8];

        // ---- B: layer-1 collapsed attention -> s[g][n] ----
        #pragma unroll
        for (int it = 0; it < 2; ++it) {
            int t = l16 + 16 * it;
            if (t < 27) {
                int gg = (t >= 18) ? 2 : (t >= 9 ? 1 : 0);
                int n = t - 9 * gg;
                float on = g == nullptr ? 0.f : 0.f; (void)on;
                float oself =
                    (n == 0) ? o0 : (n == 1) ? o1 : (n == 2) ? o2 : (n == 3) ? o3 :
                    (n == 4) ? o4 : (n == 5) ? o5 : (n == 6) ? o6 : (n == 7) ? o7 : o8;
                float f1 = sC12[2 * gg] * oself;
                float c2 = sC12[2 * gg + 1];
                unsigned rbits = rowbits(am0, am1, am2, n);
                float m = -3.0e38f;
                float e0, e1, e2, e3, e4, e5, e6, e7, e8;
                #define LRELU_MASK(j, oj, ej) { \
                    float x = f1 + c2 * oj; \
                    x = x > 0.f ? x : ALPHA * x; \
                    x = ((rbits >> j) & 1) ? x : MASKV; \
                    ej = x; m = fmaxf(m, x); }
                LRELU_MASK(0, o0, e0) LRELU_MASK(1, o1, e1) LRELU_MASK(2, o2, e2)
                LRELU_MASK(3, o3, e3) LRELU_MASK(4, o4, e4) LRELU_MASK(5, o5, e5)
                LRELU_MASK(6, o6, e6) LRELU_MASK(7, o7, e7) LRELU_MASK(8, o8, e8)
                #undef LRELU_MASK
                float sum = 0.f, sw = 0.f;
                #define ACCP(ej, oj) { float p = __expf(ej - m); sum += p; sw += p * oj; }
                ACCP(e0, o0) ACCP(e1, o1) ACCP(e2, o2) ACCP(e3, o3) ACCP(e4, o4)
                ACCP(e5, o5) ACCP(e6, o6) ACCP(e7, o7) ACCP(e8, o8)
                #undef ACCP
                g[O_S + t] = sw * fast_rcp(sum);
            }
        }
        WAVE_SYNC();

        // ---- C/D: 3 K-tiles of 32; h1 f16 in LDS, GEMM via v_dot2 ----
        float acc[9][3];
        #pragma unroll
        for (int n = 0; n < 9; ++n)
            #pragma unroll
            for (int h = 0; h < 3; ++h) acc[n][h] = 0.f;

        for (int p = 0; p < 3; ++p) {
            // C: h1[n][0..31] = elu(s[p][n] * W1[32p..32p+31]) as f16
            #pragma unroll
            for (int it = 0; it < 3; ++it) {
                int t = l16 + 16 * it;
                if (t < 36) {
                    int n = t >> 2, ib = t & 3;
                    int i0 = 32 * p + 8 * ib;
                    float sv = g[O_S + p * 9 + n];
                    float4 wa = *(const float4*)&sW1[i0];
                    float4 wb = *(const float4*)&sW1[i0 + 4];
                    float v0 = sv * wa.x, v1 = sv * wa.y, v2 = sv * wa.z, v3 = sv * wa.w;
                    float v4 = sv * wb.x, v5 = sv * wb.y, v6 = sv * wb.z, v7 = sv * wb.w;
                    v0 = v0 > 0.f ? v0 : __expf(v0) - 1.f;
                    v1 = v1 > 0.f ? v1 : __expf(v1) - 1.f;
                    v2 = v2 > 0.f ? v2 : __expf(v2) - 1.f;
                    v3 = v3 > 0.f ? v3 : __expf(v3) - 1.f;
                    v4 = v4 > 0.f ? v4 : __expf(v4) - 1.f;
                    v5 = v5 > 0.f ? v5 : __expf(v5) - 1.f;
                    v6 = v6 > 0.f ? v6 : __expf(v6) - 1.f;
                    v7 = v7 > 0.f ? v7 : __expf(v7) - 1.f;
                    v8h hv;
                    hv[0] = (h16)v0; hv[1] = (h16)v1; hv[2] = (h16)v2; hv[3] = (h16)v3;
                    hv[4] = (h16)v4; hv[5] = (h16)v5; hv[6] = (h16)v6; hv[7] = (h16)v7;
                    *(v8h*)&hU[n * 32 + 8 * ib] = hv;
                }
            }
            WAVE_SYNC();

            // D: acc[n][h] += h1[n][i:i+8] . w2[c=l16+16h][i:i+8]  (all LDS)
            #pragma unroll
            for (int ib = 0; ib < 4; ++ib) {
                v8h w0 = *(const v8h*)&sW2h[(l16     ) * W2P + 32 * p + 8 * ib];
                v8h w1 = *(const v8h*)&sW2h[(l16 + 16) * W2P + 32 * p + 8 * ib];
                v8h w2 = *(const v8h*)&sW2h[(l16 + 32) * W2P + 32 * p + 8 * ib];
                #pragma unroll
                for (int n = 0; n < 9; ++n) {
                    v8h hh = *(const v8h*)&hU[n * 32 + 8 * ib];
                    acc[n][0] = dot8(hh, w0, acc[n][0]);
                    acc[n][1] = dot8(hh, w1, acc[n][1]);
                    acc[n][2] = dot8(hh, w2, acc[n][2]);
                }
            }
            WAVE_SYNC();
        }

        // ---- f1/f2 for layer-2 attention (butterfly over the 16 d-lanes) ----
        #pragma unroll
        for (int h = 0; h < 3; ++h) {
            float aa = (h == 0) ? a2a0 : (h == 1) ? a2a1 : a2a2;
            float ab = (h == 0) ? a2b0 : (h == 1) ? a2b1 : a2b2;
            #pragma unroll
            for (int n = 0; n < 9; ++n) {
                float v1 = acc[n][h] * aa;
                float v2 = acc[n][h] * ab;
                v1 += __shfl_xor(v1, 1, 16); v2 += __shfl_xor(v2, 1, 16);
                v1 += __shfl_xor(v1, 2, 16); v2 += __shfl_xor(v2, 2, 16);
                v1 += __shfl_xor(v1, 4, 16); v2 += __shfl_xor(v2, 4, 16);
                v1 += __shfl_xor(v1, 8, 16); v2 += __shfl_xor(v2, 8, 16);
                if (((h * 9 + n) & 15) == l16) {
                    g[O_F1 + h * 9 + n]  = v1;
                    g[O_F2 + h * 10 + n] = v2;
                }
            }
        }
        WAVE_SYNC();

        // ---- E1: att rows -> f16 LDS [27][12] ----
        #pragma unroll
        for (int it = 0; it < 2; ++it) {
            int t = l16 + 16 * it;
            if (t < 27) {
                int h = (t >= 18) ? 2 : (t >= 9 ? 1 : 0);
                int i = t - 9 * h;
                float f1i = g[O_F1 + t];
                const float* f2p = &g[O_F2 + h * 10];
                unsigned rbits = rowbits(am0, am1, am2, i);
                float m = -3.0e38f;
                float e0, e1, e2, e3, e4, e5, e6, e7, e8;
                #define SCORE(j, ej) { \
                    float x = f1i + f2p[j]; \
                    x = x > 0.f ? x : ALPHA * x; \
                    x = ((rbits >> j) & 1) ? x : MASKV; \
                    ej = x; m = fmaxf(m, x); }
                SCORE(0, e0) SCORE(1, e1) SCORE(2, e2) SCORE(3, e3) SCORE(4, e4)
                SCORE(5, e5) SCORE(6, e6) SCORE(7, e7) SCORE(8, e8)
                #undef SCORE
                float p0 = __expf(e0 - m), p1 = __expf(e1 - m), p2 = __expf(e2 - m);
                float p3 = __expf(e3 - m), p4 = __expf(e4 - m), p5 = __expf(e5 - m);
                float p6 = __expf(e6 - m), p7 = __expf(e7 - m), p8 = __expf(e8 - m);
                float sum = p0 + p1 + p2 + p3 + p4 + p5 + p6 + p7 + p8;
                float r = fast_rcp(sum);
                v2h q01 = { (h16)(p0 * r), (h16)(p1 * r) };
                v2h q23 = { (h16)(p2 * r), (h16)(p3 * r) };
                v2h q45 = { (h16)(p4 * r), (h16)(p5 * r) };
                v2h q67 = { (h16)(p6 * r), (h16)(p7 * r) };
                v2h q8z = { (h16)(p8 * r), (h16)0.f };
                h16* row = hU + t * 12;
                float2 s0; s0.x = __builtin_bit_cast(float, q01);
                           s0.y = __builtin_bit_cast(float, q23);
                float2 s1; s1.x = __builtin_bit_cast(float, q45);
                           s1.y = __builtin_bit_cast(float, q67);
                *(float2*)(row)     = s0;   // 24B pitch -> 8B aligned
                *(float2*)(row + 4) = s1;
                *(float*)(row + 8)  = __builtin_bit_cast(float, q8z);
            }
        }
        WAVE_SYNC();

        // ---- E2: h2 = att @ Wh2 via fdot2 (acc pre-packed to f16 pairs) ----
        #pragma unroll
        for (int h = 0; h < 3; ++h) {
            v2h aq0 = { (h16)acc[0][h], (h16)acc[1][h] };
            v2h aq1 = { (h16)acc[2][h], (h16)acc[3][h] };
            v2h aq2 = { (h16)acc[4][h], (h16)acc[5][h] };
            v2h aq3 = { (h16)acc[6][h], (h16)acc[7][h] };
            float a8 = acc[8][h];
            float t0[9];
            #pragma unroll
            for (int i = 0; i < 9; ++i) {
                const h16* row = hU + (h * 9 + i) * 12;
                v2h r01 = *(const v2h*)(row);
                v2h r23 = *(const v2h*)(row + 2);
                v2h r45 = *(const v2h*)(row + 4);
                v2h r67 = *(const v2h*)(row + 6);
                float r8 = (float)row[8];
                float a = r8 * a8;
                a = FDOT2(r01, aq0, a);
                a = FDOT2(r23, aq1, a);
                a = FDOT2(r45, aq2, a);
                a = FDOT2(r67, aq3, a);
                t0[i] = a;
            }
            #pragma unroll
            for (int i = 0; i < 9; ++i) acc[i][h] = t0[i];
        }
        WAVE_SYNC();

        // ---- F0: pack h2 -> f16 rows [9][48] at group base ----
        #pragma unroll
        for (int n = 0; n < 9; ++n)
            #pragma unroll
            for (int h = 0; h < 3; ++h)
                gh[n * 48 + l16 + 16 * h] = (h16)acc[n][h];
        WAVE_SYNC();

        // ---- F+G: scores = tanh(h2 @ Wp1 + bp1) @ Wp2 (butterfly over 16 lanes) ----
        float sp[9];
        #pragma unroll
        for (int n = 0; n < 9; ++n) sp[n] = 0.f;
        #pragma unroll
        for (int kk = 0; kk < 2; ++kk) {
            int k = kk ? kB2 : l16;
            float kwv = kk ? kw1 : kw0;
            float kbv = kk ? kb1 : kb0;
            const h16* wr = &sWp1h[k * WPP];
            v8h w0 = *(const v8h*)&wr[0],  w1 = *(const v8h*)&wr[8];
            v8h w2 = *(const v8h*)&wr[16], w3 = *(const v8h*)&wr[24];
            v8h w4 = *(const v8h*)&wr[32], w5 = *(const v8h*)&wr[40];
            #pragma unroll
            for (int n = 0; n < 9; ++n) {
                const h16* hr = &gh[n * 48];
                float a = 0.f;
                a = dot8(*(const v8h*)&hr[0],  w0, a);
                a = dot8(*(const v8h*)&hr[8],  w1, a);
                a = dot8(*(const v8h*)&hr[16], w2, a);
                a = dot8(*(const v8h*)&hr[24], w3, a);
                a = dot8(*(const v8h*)&hr[32], w4, a);
                a = dot8(*(const v8h*)&hr[40], w5, a);
                float tv = tanh_fast(a + kbv);
                sp[n] += tv * kwv;
            }
        }
        #pragma unroll
        for (int n = 0; n < 9; ++n) {
            sp[n] += __shfl_xor(sp[n], 1, 16);
            sp[n] += __shfl_xor(sp[n], 2, 16);
            sp[n] += __shfl_xor(sp[n], 4, 16);
            sp[n] += __shfl_xor(sp[n], 8, 16);
        }

        // ---- H: node softmax (bp2 cancels) + weighted sum -> out ----
        float mx = sp[0];
        #pragma unroll
        for (int n = 1; n < 9; ++n) mx = fmaxf(mx, sp[n]);
        float wn9[9], sum = 0.f;
        #pragma unroll
        for (int n = 0; n < 9; ++n) { wn9[n] = __expf(sp[n] - mx); sum += wn9[n]; }
        float r = fast_rcp(sum);
        #pragma unroll
        for (int h = 0; h < 3; ++h) {
            float ov = 0.f;
            #pragma unroll
            for (int n = 0; n < 9; ++n) ov += wn9[n] * acc[n][h];
            out[(size_t)b * 48 + l16 + 16 * h] = ov * r;
        }
        WAVE_SYNC();
    }
}

extern "C" void kernel_launch(void* const* d_in, const int* in_sizes, int n_in,
                              void* d_out, int out_size, void* d_ws, size_t ws_size,
                              hipStream_t stream) {
    const float* obs = (const float*)d_in[0];
    const float* adj = (const float*)d_in[1];
    const float* W1  = (const float*)d_in[2];
    const float* a1  = (const float*)d_in[3];
    const float* W2  = (const float*)d_in[4];
    const float* a2  = (const float*)d_in[5];
    const float* Wp1 = (const float*)d_in[6];
    const float* bp1 = (const float*)d_in[7];
    const float* Wp2 = (const float*)d_in[8];
    float* out = (float*)d_out;
    h16* ws = (h16*)d_ws;

    const int B = in_sizes[0] / 9;

    prep_kernel<<<(48 * 96 + 24 * 48 + 255) / 256, 256, 0, stream>>>(W2, Wp1, ws);

    // 4096 blocks x 8 group-slots = 32768 slots -> 4 batches/slot at B=131072
    gnn_gat_kernel<<<4096, 128, 0, stream>>>(
        obs, adj, W1, a1, a2, bp1, Wp2, ws, out, B);
}

// Round 8
// 550.556 us; speedup vs baseline: 1.6240x; 1.1996x over previous
//
#include <hip/hip_runtime.h>
#include <math.h>

typedef _Float16 h16;
typedef _Float16 v2h __attribute__((ext_vector_type(2)));
typedef _Float16 v8h __attribute__((ext_vector_type(8)));

#define ALPHA 0.2f
#define MASKV -9000000000000000.0f

constexpr int N    = 9;
constexpr int HID  = 96;
constexpr int D2   = 16;
constexpr int OUTC = 48;

// per-group LDS scratch layout (floats) -- R2 layout, h1 now f16
constexpr int O_U  = 0;    // h1 f16 [9][48] (216 floats) overlaid by att fp32 [27][12] (324)
constexpr int O_S  = 324;  // s[27] + pad
constexpr int O_F1 = 352;  // f1[27] + pad
constexpr int O_F2 = 380;  // f2[3][12]
constexpr int GSCR = 428;  // stride: 428 mod 32 = 12 -> groups spread across banks; 16B-aligned

#define FDOT2(a,b,c) __builtin_amdgcn_fdot2((a),(b),(c),false)
#define WAVE_SYNC() asm volatile("s_waitcnt lgkmcnt(0)" ::: "memory")

__device__ __forceinline__ float fast_rcp(float x) { return __builtin_amdgcn_rcpf(x); }
__device__ __forceinline__ float tanh_fast(float x) {
    float e = __expf(x + x);               // e^(2x)
    return 1.f - 2.f * fast_rcp(e + 1.f);  // inf-safe
}
__device__ __forceinline__ float elu_f(float v) {
    return v > 0.f ? v : (__expf(v) - 1.f);
}
__device__ __forceinline__ float dot8(v8h x, v8h w, float a) {
    a = FDOT2(__builtin_shufflevector(x, x, 0, 1), __builtin_shufflevector(w, w, 0, 1), a);
    a = FDOT2(__builtin_shufflevector(x, x, 2, 3), __builtin_shufflevector(w, w, 2, 3), a);
    a = FDOT2(__builtin_shufflevector(x, x, 4, 5), __builtin_shufflevector(w, w, 4, 5), a);
    a = FDOT2(__builtin_shufflevector(x, x, 6, 7), __builtin_shufflevector(w, w, 6, 7), a);
    return a;
}

// pre-pass: w2h[c][i] = (f16)W2[h][i][d], c = h*16+d  (4608 halves into d_ws)
__global__ void prep_kernel(const float* __restrict__ W2, h16* __restrict__ w2h) {
    int t = blockIdx.x * 256 + threadIdx.x;
    if (t < OUTC * HID) {
        int c = t / HID, i = t - c * HID;
        int h = c >> 4, d = c & 15;
        w2h[t] = (h16)W2[(h * HID + i) * D2 + d];
    }
}

// Shape cloned from round-2 (the only traffic-clean config: FETCH 3.4 MB,
// VGPR 128 no spill). Changes: D-stage f16 dot2 (halves the hot VALU), h1
// tile f16 (LDS 37->28 KB), prefetch double-buffers removed (-48 live regs
// so the allocator is no longer at the 128-reg cliff that spilled R4).
__global__ __launch_bounds__(128, 2) void gnn_gat_kernel(
    const float* __restrict__ obs, const float* __restrict__ adj,
    const float* __restrict__ W1,  const float* __restrict__ a1,
    const float* __restrict__ a2,
    const float* __restrict__ Wp1, const float* __restrict__ bp1,
    const float* __restrict__ Wp2, const float* __restrict__ bp2,
    const h16* __restrict__ w2h,
    float* __restrict__ out, int B)
{
    __shared__ float sW1[96];
    __shared__ __align__(16) float smem[2][8][GSCR];

    const int tid  = threadIdx.x;
    const int wv   = tid >> 6;
    const int lane = tid & 63;
    const int q    = lane >> 3;   // group (sub-batch) within wave
    const int l8   = lane & 7;    // lane within group
    float* scr = smem[wv][q];
    h16* hU = (h16*)&scr[O_U];    // h1 tile as halves [9][48]

    for (int t = lane; t < 96; t += 64) sW1[t] = W1[t];

    // layer-1 collapsed coefficients c1[g], c2[g]
    float c12[6];
    #pragma unroll
    for (int g = 0; g < 3; ++g) {
        float s1 = 0.f, s2 = 0.f;
        for (int d = 0; d < 32; ++d) {
            float w = W1[g * 32 + d];
            s1 += w * a1[g * 64 + d];
            s2 += w * a1[g * 64 + 32 + d];
        }
        c12[2 * g] = s1; c12[2 * g + 1] = s2;
    }
    // a2 slices (lane owns d = l8 and d = l8+8 per head)
    float a2a0[3], a2a1[3], a2b0[3], a2b1[3];
    #pragma unroll
    for (int h = 0; h < 3; ++h) {
        a2a0[h] = a2[h * 32 + l8];
        a2a1[h] = a2[h * 32 + 8 + l8];
        a2b0[h] = a2[h * 32 + 16 + l8];
        a2b1[h] = a2[h * 32 + 24 + l8];
    }
    // adjacency bitmasks
    unsigned am[3];
    #pragma unroll
    for (int r = 0; r < 3; ++r) {
        unsigned u = 0;
        for (int t = 0; t < 27; ++t)
            u |= (adj[r * 27 + t] > 0.f ? 1u : 0u) << t;
        am[r] = u;
    }
    const float bp2r = bp2[0];

    const int gid0    = (blockIdx.x * 2 + wv) * 8 + q;
    const int nw      = gridDim.x * 16;

    for (int b = gid0; b < B; b += nw) {
        // ---- A: obs -> regs ----
        float o_r[9];
        #pragma unroll
        for (int j = 0; j < 9; ++j) o_r[j] = obs[(size_t)b * 9 + j];

        // ---- B: layer-1 attention -> s[g][n] (27 items over 8 lanes) ----
        for (int t = l8; t < 27; t += 8) {
            int g = (t >= 18) ? 2 : (t >= 9 ? 1 : 0);
            int n = t - 9 * g;
            float c1 = c12[2 * g], c2 = c12[2 * g + 1];
            float f1 = c1 * o_r[n];
            unsigned rbits = (am[n / 3] >> (9 * (n % 3))) & 0x1FFu;
            float e[9], m = -3.0e38f;
            #pragma unroll
            for (int j = 0; j < 9; ++j) {
                float x = f1 + c2 * o_r[j];
                x = x > 0.f ? x : ALPHA * x;
                x = ((rbits >> j) & 1) ? x : MASKV;
                e[j] = x; m = fmaxf(m, x);
            }
            float sum = 0.f, sw = 0.f;
            #pragma unroll
            for (int j = 0; j < 9; ++j) {
                float p = __expf(e[j] - m);
                sum += p; sw += p * o_r[j];
            }
            scr[O_S + t] = sw * fast_rcp(sum);
        }
        WAVE_SYNC();

        // ---- C/D: two K-halves of 48; h1 f16 in LDS; GEMM via v_dot2 ----
        float acc[9][6];
        #pragma unroll
        for (int n = 0; n < 9; ++n)
            #pragma unroll
            for (int k = 0; k < 6; ++k) acc[n][k] = 0.f;

        for (int p = 0; p < 2; ++p) {
            // C: h1[n][i_loc] = elu(s * W1), packed f16x8 (54 items over 8 lanes)
            for (int t = l8; t < 54; t += 8) {
                int n = t / 6, ib = t - 6 * n;
                int i0 = 48 * p + 8 * ib;
                float sv = scr[O_S + (i0 >> 5) * 9 + n];
                float4 wa = *(const float4*)&sW1[i0];
                float4 wb = *(const float4*)&sW1[i0 + 4];
                v8h hv;
                hv[0] = (h16)elu_f(sv * wa.x);
                hv[1] = (h16)elu_f(sv * wa.y);
                hv[2] = (h16)elu_f(sv * wa.z);
                hv[3] = (h16)elu_f(sv * wa.w);
                hv[4] = (h16)elu_f(sv * wb.x);
                hv[5] = (h16)elu_f(sv * wb.y);
                hv[6] = (h16)elu_f(sv * wb.z);
                hv[7] = (h16)elu_f(sv * wb.w);
                *(v8h*)&hU[n * 48 + 8 * ib] = hv;
            }
            WAVE_SYNC();

            // D: acc[n][k] += h1[n][i:i+8] . w2[c][i:i+8]; weights f16 from global (L1-hot)
            #pragma unroll
            for (int ib = 0; ib < 6; ++ib) {
                v8h w[6];
                #pragma unroll
                for (int k = 0; k < 6; ++k)
                    w[k] = *(const v8h*)&w2h[(l8 + 8 * k) * 96 + 48 * p + 8 * ib];
                #pragma unroll
                for (int n = 0; n < 9; ++n) {
                    v8h hh = *(const v8h*)&hU[n * 48 + 8 * ib];
                    #pragma unroll
                    for (int k = 0; k < 6; ++k)
                        acc[n][k] = dot8(hh, w[k], acc[n][k]);
                }
            }
            WAVE_SYNC();
        }

        // ---- f1/f2 for layer-2 attention: butterfly over the 8 d-lanes ----
        #pragma unroll
        for (int h = 0; h < 3; ++h) {
            #pragma unroll
            for (int n = 0; n < 9; ++n) {
                float v1 = acc[n][2 * h] * a2a0[h] + acc[n][2 * h + 1] * a2a1[h];
                float v2 = acc[n][2 * h] * a2b0[h] + acc[n][2 * h + 1] * a2b1[h];
                #pragma unroll
                for (int mm = 1; mm <= 4; mm <<= 1) {
                    v1 += __shfl_xor(v1, mm, 8);
                    v2 += __shfl_xor(v2, mm, 8);
                }
                if (((h * 9 + n) & 7) == l8) {
                    scr[O_F1 + h * 9 + n]  = v1;
                    scr[O_F2 + h * 12 + n] = v2;
                }
            }
        }
        WAVE_SYNC();

        // ---- E1: att rows (27 over 8 lanes) -> fp32 LDS [27][12], overlays h1 ----
        for (int t = l8; t < 27; t += 8) {
            int h = (t >= 18) ? 2 : (t >= 9 ? 1 : 0);
            int i = t - 9 * h;
            float f1i = scr[O_F1 + t];
            float f2r[9];
            #pragma unroll
            for (int j = 0; j < 9; ++j) f2r[j] = scr[O_F2 + h * 12 + j];
            unsigned rbits = (am[i / 3] >> (9 * (i % 3))) & 0x1FFu;
            float e[9], m = -3.0e38f;
            #pragma unroll
            for (int j = 0; j < 9; ++j) {
                float x = f1i + f2r[j];
                x = x > 0.f ? x : ALPHA * x;
                x = ((rbits >> j) & 1) ? x : MASKV;
                e[j] = x; m = fmaxf(m, x);
            }
            float p[9], sum = 0.f;
            #pragma unroll
            for (int j = 0; j < 9; ++j) { p[j] = __expf(e[j] - m); sum += p[j]; }
            float r = fast_rcp(sum);
            float4 p03 = { p[0] * r, p[1] * r, p[2] * r, p[3] * r };
            float4 p47 = { p[4] * r, p[5] * r, p[6] * r, p[7] * r };
            *(float4*)&scr[O_U + t * 12]     = p03;
            *(float4*)&scr[O_U + t * 12 + 4] = p47;
            scr[O_U + t * 12 + 8] = p[8] * r;
        }
        WAVE_SYNC();

        // ---- E2: h2 = att @ Wh2, in place into acc ----
        #pragma unroll
        for (int h = 0; h < 3; ++h) {
            float t0[9], t1[9];
            #pragma unroll
            for (int i = 0; i < 9; ++i) {
                const float4 r03 = *(const float4*)&scr[O_U + (h * 9 + i) * 12];
                const float4 r47 = *(const float4*)&scr[O_U + (h * 9 + i) * 12 + 4];
                const float  r8  = scr[O_U + (h * 9 + i) * 12 + 8];
                t0[i] = r03.x * acc[0][2*h] + r03.y * acc[1][2*h] + r03.z * acc[2][2*h]
                      + r03.w * acc[3][2*h] + r47.x * acc[4][2*h] + r47.y * acc[5][2*h]
                      + r47.z * acc[6][2*h] + r47.w * acc[7][2*h] + r8 * acc[8][2*h];
                t1[i] = r03.x * acc[0][2*h+1] + r03.y * acc[1][2*h+1] + r03.z * acc[2][2*h+1]
                      + r03.w * acc[3][2*h+1] + r47.x * acc[4][2*h+1] + r47.y * acc[5][2*h+1]
                      + r47.z * acc[6][2*h+1] + r47.w * acc[7][2*h+1] + r8 * acc[8][2*h+1];
            }
            #pragma unroll
            for (int i = 0; i < 9; ++i) { acc[i][2*h] = t0[i]; acc[i][2*h+1] = t1[i]; }
        }

        // ---- F+G: scores = tanh(h2 @ Wp1 + bp1) @ Wp2 + bp2 (8-lane butterfly) ----
        float score[9];
        #pragma unroll
        for (int n = 0; n < 9; ++n) score[n] = bp2r;

        for (int kb = 0; kb < 6; ++kb) {
            float4 wp[6];
            #pragma unroll
            for (int k = 0; k < 6; ++k)
                wp[k] = *(const float4*)&Wp1[(l8 + 8 * k) * 24 + 4 * kb];
            float4 bq = *(const float4*)&bp1[4 * kb];
            float4 wq = *(const float4*)&Wp2[4 * kb];
            #pragma unroll
            for (int n = 0; n < 9; ++n) {
                float4 part;
                part.x = acc[n][0]*wp[0].x + acc[n][1]*wp[1].x + acc[n][2]*wp[2].x
                       + acc[n][3]*wp[3].x + acc[n][4]*wp[4].x + acc[n][5]*wp[5].x;
                part.y = acc[n][0]*wp[0].y + acc[n][1]*wp[1].y + acc[n][2]*wp[2].y
                       + acc[n][3]*wp[3].y + acc[n][4]*wp[4].y + acc[n][5]*wp[5].y;
                part.z = acc[n][0]*wp[0].z + acc[n][1]*wp[1].z + acc[n][2]*wp[2].z
                       + acc[n][3]*wp[3].z + acc[n][4]*wp[4].z + acc[n][5]*wp[5].z;
                part.w = acc[n][0]*wp[0].w + acc[n][1]*wp[1].w + acc[n][2]*wp[2].w
                       + acc[n][3]*wp[3].w + acc[n][4]*wp[4].w + acc[n][5]*wp[5].w;
                #pragma unroll
                for (int mm = 1; mm <= 4; mm <<= 1) {
                    part.x += __shfl_xor(part.x, mm, 8);
                    part.y += __shfl_xor(part.y, mm, 8);
                    part.z += __shfl_xor(part.z, mm, 8);
                    part.w += __shfl_xor(part.w, mm, 8);
                }
                float tx = tanh_fast(part.x + bq.x);
                float ty = tanh_fast(part.y + bq.y);
                float tz = tanh_fast(part.z + bq.z);
                float tw = tanh_fast(part.w + bq.w);
                score[n] += tx * wq.x + ty * wq.y + tz * wq.z + tw * wq.w;
            }
        }

        // ---- H: node softmax + weighted sum -> out[b][48] ----
        float mx = score[0];
        #pragma unroll
        for (int n = 1; n < 9; ++n) mx = fmaxf(mx, score[n]);
        float wn9[9], sum = 0.f;
        #pragma unroll
        for (int n = 0; n < 9; ++n) { wn9[n] = __expf(score[n] - mx); sum += wn9[n]; }
        float r = fast_rcp(sum);
        #pragma unroll
        for (int n = 0; n < 9; ++n) wn9[n] *= r;
        #pragma unroll
        for (int k = 0; k < 6; ++k) {
            float ov = 0.f;
            #pragma unroll
            for (int n = 0; n < 9; ++n) ov += wn9[n] * acc[n][k];
            out[(size_t)b * 48 + l8 + 8 * k] = ov;
        }
        WAVE_SYNC();
    }
}

extern "C" void kernel_launch(void* const* d_in, const int* in_sizes, int n_in,
                              void* d_out, int out_size, void* d_ws, size_t ws_size,
                              hipStream_t stream) {
    const float* obs = (const float*)d_in[0];
    const float* adj = (const float*)d_in[1];
    const float* W1  = (const float*)d_in[2];
    const float* a1  = (const float*)d_in[3];
    const float* W2  = (const float*)d_in[4];
    const float* a2  = (const float*)d_in[5];
    const float* Wp1 = (const float*)d_in[6];
    const float* bp1 = (const float*)d_in[7];
    const float* Wp2 = (const float*)d_in[8];
    const float* bp2 = (const float*)d_in[9];
    float* out = (float*)d_out;
    h16* w2h = (h16*)d_ws;

    const int B = in_sizes[0] / N;

    prep_kernel<<<(OUTC * HID + 255) / 256, 256, 0, stream>>>(W2, w2h);

    // 2048 blocks x 2 waves x 8 groups = 32768 group-slots (R2 dispatch shape)
    gnn_gat_kernel<<<2048, 128, 0, stream>>>(
        obs, adj, W1, a1, a2, Wp1, bp1, Wp2, bp2, w2h, out, B);
}